// Round 3
// baseline (628.580 us; speedup 1.0000x reference)
//
#include <hip/hip_runtime.h>

// ---------------------------------------------------------------------------
// AllTnn: locally-connected net, B=128, fp32 (FC via bf16 MFMA).
//  L0: x[128,3,224,224] * w0[55,55,16,3,8,8] (s4) + b0 -> [128,16,55,55]
//      flatten 4x4 -> [128,220,220], relu, LN(220x220)*g0+be0, maxpool2 -> P[128,110,110]
//  L1: P * w1[53,53,9,1,6,6] (s2) + b1 -> [128,9,53,53]
//      flatten 3x3 -> [128,159,159], relu, LN(159x159)*g1+be1
//  FC: [128,25281] @ fcw[1000,25281]^T + fcb -> softmax -> out[128,1000]
// ---------------------------------------------------------------------------

typedef __attribute__((ext_vector_type(8))) short short8;
typedef __attribute__((ext_vector_type(4))) float float4v;

__device__ __forceinline__ short f2bf(float f) {
    unsigned u = __float_as_uint(f);
    u += 0x7FFFu + ((u >> 16) & 1u);        // round-to-nearest-even
    return (short)(u >> 16);
}

// ======================= conv0: locally connected layer 0 ===================
// block = 128 thr, one (oh,ow) location; 128 b x 16 o outputs, K=192.
// LDS: w tile [k][o] stride 20 (full K, 15.4 KB), x slice [b][32k] XOR-swizzled
// (16.4 KB) -> 31.7 KB/block -> 5 blocks/CU (10 waves/CU).
// Register-prefetch pipeline: slice s+1 global loads issued before compute(s).
__global__ __launch_bounds__(128) void k_conv0(const float* __restrict__ x,
                                               const float* __restrict__ w0,
                                               const float* __restrict__ b0,
                                               float* __restrict__ y0)
{
    __shared__ float wl[192 * 20];
    __shared__ float xl[128 * 32];
    const int t = threadIdx.x;            // 0..127
    const int loc = blockIdx.x;
    const int oh = loc / 55, ow = loc % 55;
    const float* wbase = w0 + loc * 3072;

    // stage w: [k][o] stride 20. 768 float4 quads, 6 per thread.
    #pragma unroll
    for (int i = 0; i < 6; ++i) {
        int q   = t + (i << 7);
        int o_r = q & 15;
        int kq  = q >> 4;                 // [0,48)
        float4 wv = *(const float4*)(wbase + o_r * 192 + (kq << 2));
        wl[(kq * 4 + 0) * 20 + o_r] = wv.x;
        wl[(kq * 4 + 1) * 20 + o_r] = wv.y;
        wl[(kq * 4 + 2) * 20 + o_r] = wv.z;
        wl[(kq * 4 + 3) * 20 + o_r] = wv.w;
    }

    // x slice prefetch registers (8 float4 = 32 VGPR)
    float4 xv[8];
    #pragma unroll
    for (int i = 0; i < 8; ++i) {         // prefetch slice 0
        int q   = t + (i << 7);
        int b_r = q >> 3, c = q & 7;
        int k   = c << 2;
        int ch  = k >> 6, rw = (k >> 3) & 7, col = k & 7;
        xv[i] = *(const float4*)(x + ((b_r * 3 + ch) * 224 + (oh << 2) + rw) * 224
                                   + (ow << 2) + col);
    }

    const int oP = t & 3;        // o quad base = oP*4
    const int bP = t >> 2;       // b quad base = bP*4, [0,32)
    const int sw = bP & 7;       // swizzle key
    float acc[4][4] = {};

    for (int s = 0; s < 6; ++s) {        // K slices of 32
        __syncthreads();                 // prior slice's LDS consumers done
        #pragma unroll
        for (int i = 0; i < 8; ++i) {    // regs -> LDS
            int q   = t + (i << 7);
            int b_r = q >> 3, c = q & 7;
            int cs  = c ^ ((b_r >> 2) & 7);
            *(float4*)&xl[(b_r << 5) + (cs << 2)] = xv[i];
        }
        __syncthreads();
        if (s < 5) {                     // issue next slice's loads now;
            #pragma unroll               // latency hides under compute below
            for (int i = 0; i < 8; ++i) {
                int q   = t + (i << 7);
                int b_r = q >> 3, c = q & 7;
                int k   = ((s + 1) << 5) + (c << 2);
                int ch  = k >> 6, rw = (k >> 3) & 7, col = k & 7;
                xv[i] = *(const float4*)(x + ((b_r * 3 + ch) * 224 + (oh << 2) + rw) * 224
                                           + (ow << 2) + col);
            }
        }
        #pragma unroll
        for (int k4 = 0; k4 < 8; ++k4) {
            float wv[4][4];
            #pragma unroll
            for (int u = 0; u < 4; ++u) {
                float4 wq = *(const float4*)&wl[((s << 5) + (k4 << 2) + u) * 20 + (oP << 2)];
                wv[u][0] = wq.x; wv[u][1] = wq.y; wv[u][2] = wq.z; wv[u][3] = wq.w;
            }
            const int cc = ((k4 ^ sw) << 2);
            float xr[4][4];
            #pragma unroll
            for (int i2 = 0; i2 < 4; ++i2) {
                float4 xq = *(const float4*)&xl[(((bP << 2) + i2) << 5) + cc];
                xr[i2][0] = xq.x; xr[i2][1] = xq.y; xr[i2][2] = xq.z; xr[i2][3] = xq.w;
            }
            #pragma unroll
            for (int i2 = 0; i2 < 4; ++i2)
                #pragma unroll
                for (int u = 0; u < 4; ++u)
                    #pragma unroll
                    for (int j = 0; j < 4; ++j)
                        acc[i2][j] += xr[i2][u] * wv[u][j];
        }
    }

    #pragma unroll
    for (int i2 = 0; i2 < 4; ++i2) {
        int b = (bP << 2) + i2;
        float4 outv;
        float ov[4];
        #pragma unroll
        for (int j = 0; j < 4; ++j) {
            float v = acc[i2][j] + b0[((oP << 2) + j) * 3025 + loc];
            ov[j] = v > 0.f ? v : 0.f;
        }
        outv.x = ov[0]; outv.y = ov[1]; outv.z = ov[2]; outv.w = ov[3];
        // flatten: row = 4*oh + oP ; col = 4*ow + (o&3)
        *(float4*)(y0 + b * 48400 + ((oh << 2) + oP) * 220 + (ow << 2)) = outv;
    }
}

// ======================= per-sample mean / rstd =============================
__global__ void k_stats(const float* __restrict__ src, float2* __restrict__ stats, int count)
{
    const int b = blockIdx.x, t = threadIdx.x;
    const float* p = src + (long)b * count;
    const int nq = count >> 2;
    float s = 0.f, s2 = 0.f;
    for (int i = t; i < nq; i += 256) {
        float4 v = *(const float4*)(p + (i << 2));
        s  += (v.x + v.y) + (v.z + v.w);
        s2 += (v.x * v.x + v.y * v.y) + (v.z * v.z + v.w * v.w);
    }
    if (t == 0 && (count & 3)) {
        for (int i = nq << 2; i < count; ++i) { float v = p[i]; s += v; s2 += v * v; }
    }
    #pragma unroll
    for (int off = 32; off > 0; off >>= 1) {
        s  += __shfl_down(s,  off, 64);
        s2 += __shfl_down(s2, off, 64);
    }
    __shared__ float rs[4], rs2[4];
    if ((t & 63) == 0) { rs[t >> 6] = s; rs2[t >> 6] = s2; }
    __syncthreads();
    if (t == 0) {
        float S  = rs[0] + rs[1] + rs[2] + rs[3];
        float S2 = rs2[0] + rs2[1] + rs2[2] + rs2[3];
        float m  = S / count;
        float var = S2 / count - m * m;
        stats[b] = make_float2(m, rsqrtf(var + 1e-5f));
    }
}

// =============== layer0: normalize + affine + 2x2 maxpool ===================
__global__ void k_pool(const float* __restrict__ y0, const float2* __restrict__ st,
                       const float* __restrict__ g0, const float* __restrict__ be0,
                       float* __restrict__ P)
{
    int idx = blockIdx.x * 256 + threadIdx.x;
    if (idx >= 128 * 110 * 110) return;
    int b = idx / 12100, r = idx % 12100;
    int ph = r / 110, pw = r % 110;
    float2 s = st[b];
    int gb = (ph * 220 + pw) * 2;        // 2ph*220 + 2pw
    const float* yb = y0 + b * 48400 + gb;
    float2 a0 = *(const float2*)yb;
    float2 a1 = *(const float2*)(yb + 220);
    float2 ga0 = *(const float2*)(g0 + gb),  ga1 = *(const float2*)(g0 + gb + 220);
    float2 ba0 = *(const float2*)(be0 + gb), ba1 = *(const float2*)(be0 + gb + 220);
    float n0 = (a0.x - s.x) * s.y * ga0.x + ba0.x;
    float n1 = (a0.y - s.x) * s.y * ga0.y + ba0.y;
    float n2 = (a1.x - s.x) * s.y * ga1.x + ba1.x;
    float n3 = (a1.y - s.x) * s.y * ga1.y + ba1.y;
    P[idx] = fmaxf(fmaxf(n0, n1), fmaxf(n2, n3));
}

// ======================= conv1: locally connected layer 1 ===================
// block = 128 thr (lane = b), one (oh,ow) location; 9 o, K=36.
__global__ __launch_bounds__(128) void k_conv1(const float* __restrict__ P,
                                               const float* __restrict__ w1,
                                               const float* __restrict__ b1,
                                               float* __restrict__ y1)
{
    __shared__ float wloc[324];
    __shared__ float pat[128 * 64];      // [b][16 chunks] XOR-swizzled
    const int t = threadIdx.x;
    const int loc = blockIdx.x;
    const int oh = loc / 53, ow = loc % 53;
    for (int e = t; e < 324; e += 128) wloc[e] = w1[loc * 324 + e];
    #pragma unroll
    for (int i = 0; i < 9; ++i) {
        int q = t + (i << 7);            // [0,1152)
        int b_r = q / 9, c = q % 9;
        float pv[4];
        #pragma unroll
        for (int u = 0; u < 4; ++u) {
            int sidx = (c << 2) + u;     // < 36
            int ki = sidx / 6, kj = sidx % 6;
            pv[u] = P[b_r * 12100 + ((oh << 1) + ki) * 110 + (ow << 1) + kj];
        }
        float4 pq; pq.x = pv[0]; pq.y = pv[1]; pq.z = pv[2]; pq.w = pv[3];
        *(float4*)&pat[(b_r << 6) + ((c ^ (b_r & 15)) << 2)] = pq;
    }
    __syncthreads();
    const int b = t;
    float acc[9];
    #pragma unroll
    for (int o = 0; o < 9; ++o) acc[o] = b1[o * 2809 + loc];
    #pragma unroll
    for (int s4 = 0; s4 < 9; ++s4) {
        float4 pq = *(const float4*)&pat[(b << 6) + ((s4 ^ (b & 15)) << 2)];
        #pragma unroll
        for (int o = 0; o < 9; ++o) {
            float4 wq = *(const float4*)&wloc[o * 36 + (s4 << 2)];
            acc[o] += pq.x * wq.x + pq.y * wq.y + pq.z * wq.z + pq.w * wq.w;
        }
    }
    #pragma unroll
    for (int o = 0; o < 9; ++o) {
        float v = acc[o] > 0.f ? acc[o] : 0.f;
        // flatten 3x3: row = 3*oh + o/3, col = 3*ow + o%3
        y1[b * 25281 + (3 * oh + o / 3) * 159 + 3 * ow + o % 3] = v;
    }
}

// ============ layer1 normalize -> hb[b][25600] (bf16, zero-padded) ==========
__global__ void k_normb(const float* __restrict__ y1, const float2* __restrict__ st,
                        const float* __restrict__ g1, const float* __restrict__ be1,
                        unsigned short* __restrict__ hb)
{
    int idx = blockIdx.x * 256 + threadIdx.x;   // < 128*25600
    int b = idx / 25600, k = idx % 25600;
    float v = 0.f;
    if (k < 25281) {
        float2 s = st[b];
        v = (y1[b * 25281 + k] - s.x) * s.y * g1[k] + be1[k];
    }
    hb[idx] = (unsigned short)f2bf(v);
}

// =============== FC: 128x1000 GEMM, bf16 MFMA, K-split 50 ===================
// grid = (16 n-blocks of 64) x (50 k-splits of 512); 256 thr = 4 waves.
// wave owns a 16-col stripe x full M=128 (8 MFMA 16x16x32 tiles, no LDS).
// fcw converted fp32->bf16 on the fly (fetched once); hb is bf16, L2/L3-hot.
__global__ __launch_bounds__(256) void k_fc_mfma(const unsigned short* __restrict__ hb,
                                                 const float* __restrict__ fcw,
                                                 float* __restrict__ pp)
{
    const int lane = threadIdx.x & 63;
    const int wave = threadIdx.x >> 6;
    const int n0   = (blockIdx.x << 6) + (wave << 4);   // wave's col base
    const int k0   = blockIdx.y << 9;                   // 512 K per block
    const int m16  = lane & 15;
    const int q    = lane >> 4;                         // 0..3
    const int nc   = n0 + m16;                          // this lane's col
    const int nrow = nc < 1000 ? nc : 999;              // clamp (cols>=1000 ignored)
    const long wrow = (long)nrow * 25281;

    float4v acc[8];
    #pragma unroll
    for (int i = 0; i < 8; ++i) acc[i] = (float4v){0.f, 0.f, 0.f, 0.f};

    const unsigned short* ha = hb + m16 * 25600;        // A row for this lane

    for (int c = 0; c < 16; ++c) {                      // 16 k-chunks of 32
        const int kb = k0 + (c << 5) + (q << 3);        // this lane's 8-k base
        // ---- B fragment: fcw[nrow][kb..kb+7], fp32 -> bf16 (row stride odd
        //      => scalar dword loads; 4 quads/row still cover 128B contiguous)
        long widx = wrow + kb;
        short8 bf;
        if (widx + 8 <= 25281000L) {
            #pragma unroll
            for (int j = 0; j < 8; ++j) bf[j] = f2bf(fcw[widx + j]);
        } else {                                        // tail of last row only
            #pragma unroll
            for (int j = 0; j < 8; ++j) {
                long e = widx + j;
                bf[j] = f2bf(e < 25281000L ? fcw[e] : 0.f);
            }
        }
        // ---- A fragments (bf16 direct, 16B aligned) + 8 MFMAs over M=128
        #pragma unroll
        for (int mt = 0; mt < 8; ++mt) {
            short8 af = *(const short8*)(ha + mt * 16 * 25600 + kb);
            acc[mt] = __builtin_amdgcn_mfma_f32_16x16x32_bf16(af, bf, acc[mt], 0, 0, 0);
        }
    }

    // ---- store partials: D row = q*4+i (within 16-tile), col = m16
    float* prow = pp + ((size_t)blockIdx.y << 17);      // [bz][128][1024]
    #pragma unroll
    for (int mt = 0; mt < 8; ++mt) {
        const int mb = (mt << 4) + (q << 2);
        #pragma unroll
        for (int i = 0; i < 4; ++i)
            prow[(size_t)(mb + i) * 1024 + nc] = acc[mt][i];
    }
}

// ================= reduce K-partials + bias + softmax =======================
__global__ void k_softmax(const float* __restrict__ partials, const float* __restrict__ fcb,
                          float* __restrict__ out)
{
    const int b = blockIdx.x, t = threadIdx.x;
    float v[4];
    float mx = -3.4e38f;
    #pragma unroll
    for (int i = 0; i < 4; ++i) {
        int o = t + (i << 8);
        float s = -3.4e38f;
        if (o < 1000) {
            s = fcb[o];
            for (int bz = 0; bz < 50; ++bz)
                s += partials[(((bz << 7) + b) << 10) + o];
        }
        v[i] = s;
        mx = fmaxf(mx, s);
    }
    __shared__ float red[4], red2[4];
    #pragma unroll
    for (int off = 32; off > 0; off >>= 1) mx = fmaxf(mx, __shfl_down(mx, off, 64));
    if ((t & 63) == 0) red[t >> 6] = mx;
    __syncthreads();
    float M = fmaxf(fmaxf(red[0], red[1]), fmaxf(red[2], red[3]));
    float se = 0.f;
    #pragma unroll
    for (int i = 0; i < 4; ++i) {
        int o = t + (i << 8);
        if (o < 1000) { v[i] = expf(v[i] - M); se += v[i]; }
    }
    #pragma unroll
    for (int off = 32; off > 0; off >>= 1) se += __shfl_down(se, off, 64);
    if ((t & 63) == 0) red2[t >> 6] = se;
    __syncthreads();
    float inv = 1.f / (red2[0] + red2[1] + red2[2] + red2[3]);
    #pragma unroll
    for (int i = 0; i < 4; ++i) {
        int o = t + (i << 8);
        if (o < 1000) out[b * 1000 + o] = v[i] * inv;
    }
}

// ===========================================================================
extern "C" void kernel_launch(void* const* d_in, const int* in_sizes, int n_in,
                              void* d_out, int out_size, void* d_ws, size_t ws_size,
                              hipStream_t stream)
{
    const float* x   = (const float*)d_in[0];
    const float* w0  = (const float*)d_in[1];
    const float* b0  = (const float*)d_in[2];
    const float* g0  = (const float*)d_in[3];
    const float* be0 = (const float*)d_in[4];
    const float* w1  = (const float*)d_in[5];
    const float* b1  = (const float*)d_in[6];
    const float* g1  = (const float*)d_in[7];
    const float* be1 = (const float*)d_in[8];
    const float* fcw = (const float*)d_in[9];
    const float* fcb = (const float*)d_in[10];
    float* out = (float*)d_out;
    float* ws  = (float*)d_ws;

    // workspace layout (floats), max 12,618,880 (~50.5 MB):
    //   y0  [0 .. 6,195,200)                 128*220*220
    //   st0 [6,195,200 .. 6,195,456)         128 float2
    //   P   [6,195,456 .. 7,744,256)         128*110*110
    //   y1  [7,744,256 .. 10,980,224)        128*159*159
    //   st1 [10,980,224 .. 10,980,480)       128 float2
    //   hb  [10,980,480 .. 12,618,880)       128*25600 bf16 (ushort)
    //   pp  [0 .. 6,553,600)                 50*128*1024 -- overlays y0/st0/P
    //       (y0/st0/P are dead before k_fc_mfma runs)
    float*  y0  = ws;
    float2* st0 = (float2*)(ws + 6195200);
    float*  P   = ws + 6195456;
    float*  y1  = ws + 7744256;
    float2* st1 = (float2*)(ws + 10980224);
    unsigned short* hb = (unsigned short*)(ws + 10980480);
    float*  pp  = ws;

    hipLaunchKernelGGL(k_conv0,   dim3(3025),    dim3(128), 0, stream, x, w0, b0, y0);
    hipLaunchKernelGGL(k_stats,   dim3(128),     dim3(256), 0, stream, y0, st0, 48400);
    hipLaunchKernelGGL(k_pool,    dim3(6050),    dim3(256), 0, stream, y0, st0, g0, be0, P);
    hipLaunchKernelGGL(k_conv1,   dim3(2809),    dim3(128), 0, stream, P, w1, b1, y1);
    hipLaunchKernelGGL(k_stats,   dim3(128),     dim3(256), 0, stream, y1, st1, 25281);
    hipLaunchKernelGGL(k_normb,   dim3(12800),   dim3(256), 0, stream, y1, st1, g1, be1, hb);
    hipLaunchKernelGGL(k_fc_mfma, dim3(16, 50),  dim3(256), 0, stream, hb, fcw, pp);
    hipLaunchKernelGGL(k_softmax, dim3(128),     dim3(256), 0, stream, pp, fcb, out);
}

// Round 4
// 572.108 us; speedup vs baseline: 1.0987x; 1.0987x over previous
//
#include <hip/hip_runtime.h>

// ---------------------------------------------------------------------------
// AllTnn: locally-connected net, B=128, fp32 (FC via bf16 MFMA).
//  L0: x[128,3,224,224] * w0[55,55,16,3,8,8] (s4) + b0 -> [128,16,55,55]
//      flatten 4x4 -> [128,220,220], relu, LN(220x220)*g0+be0, maxpool2 -> P[128,110,110]
//  L1: P * w1[53,53,9,1,6,6] (s2) + b1 -> [128,9,53,53]
//      flatten 3x3 -> [128,159,159], relu, LN(159x159)*g1+be1
//  FC: [128,25281] @ fcw[1000,25281]^T + fcb -> softmax -> out[128,1000]
// ---------------------------------------------------------------------------

typedef __attribute__((ext_vector_type(8))) short short8;
typedef __attribute__((ext_vector_type(4))) float float4v;

__device__ __forceinline__ short f2bf(float f) {
    unsigned u = __float_as_uint(f);
    u += 0x7FFFu + ((u >> 16) & 1u);        // round-to-nearest-even
    return (short)(u >> 16);
}

// ======================= conv0: locally connected layer 0 ===================
// block = 256 thr = 2 sub-blocks of 128, each one (oh,ow) location; the PAIR
// of adjacent ow locations shares the CU's L1/XCD-L2 so overlapping x lines
// are fetched once and 16B y0 store chunks merge into lines (R2: 322+37 MB
// vs R3's 1-loc blocks: 699+337 MB).
// Register-prefetch pipeline (R3): slice s+1 global loads issued before
// compute(s) -> VMEM latency hides under FMAs; converts to BW-bound.
__global__ __launch_bounds__(256) void k_conv0(const float* __restrict__ x,
                                               const float* __restrict__ w0,
                                               const float* __restrict__ b0,
                                               float* __restrict__ y0)
{
    __shared__ float wl[2][192 * 20];
    __shared__ float xl[2][128 * 32];
    const int g = threadIdx.x >> 7;
    const int t = threadIdx.x & 127;
    int loc = blockIdx.x * 2 + g;
    const bool active = (loc < 3025);
    if (!active) loc = 3024;              // clamp: valid addresses, writes guarded
    const int oh = loc / 55, ow = loc % 55;
    const float* wbase = w0 + loc * 3072;

    // stage w: [k][o] stride 20. 768 float4 quads, 6 per thread.
    #pragma unroll
    for (int i = 0; i < 6; ++i) {
        int q   = t + (i << 7);
        int o_r = q & 15;
        int kq  = q >> 4;                 // [0,48)
        float4 wv = *(const float4*)(wbase + o_r * 192 + (kq << 2));
        wl[g][(kq * 4 + 0) * 20 + o_r] = wv.x;
        wl[g][(kq * 4 + 1) * 20 + o_r] = wv.y;
        wl[g][(kq * 4 + 2) * 20 + o_r] = wv.z;
        wl[g][(kq * 4 + 3) * 20 + o_r] = wv.w;
    }

    // x slice prefetch registers (8 float4 = 32 VGPR)
    float4 xv[8];
    #pragma unroll
    for (int i = 0; i < 8; ++i) {         // prefetch slice 0
        int q   = t + (i << 7);
        int b_r = q >> 3, c = q & 7;
        int k   = c << 2;
        int ch  = k >> 6, rw = (k >> 3) & 7, col = k & 7;
        xv[i] = *(const float4*)(x + ((b_r * 3 + ch) * 224 + (oh << 2) + rw) * 224
                                   + (ow << 2) + col);
    }

    const int oP = t & 3;        // o quad base = oP*4
    const int bP = t >> 2;       // b quad base = bP*4, [0,32)
    const int sw = bP & 7;       // swizzle key
    float acc[4][4] = {};

    for (int s = 0; s < 6; ++s) {        // K slices of 32
        __syncthreads();                 // prior slice's LDS consumers done
        #pragma unroll
        for (int i = 0; i < 8; ++i) {    // regs -> LDS
            int q   = t + (i << 7);
            int b_r = q >> 3, c = q & 7;
            int cs  = c ^ ((b_r >> 2) & 7);
            *(float4*)&xl[g][(b_r << 5) + (cs << 2)] = xv[i];
        }
        __syncthreads();
        if (s < 5) {                     // issue next slice's loads now;
            #pragma unroll               // latency hides under compute below
            for (int i = 0; i < 8; ++i) {
                int q   = t + (i << 7);
                int b_r = q >> 3, c = q & 7;
                int k   = ((s + 1) << 5) + (c << 2);
                int ch  = k >> 6, rw = (k >> 3) & 7, col = k & 7;
                xv[i] = *(const float4*)(x + ((b_r * 3 + ch) * 224 + (oh << 2) + rw) * 224
                                           + (ow << 2) + col);
            }
        }
        #pragma unroll
        for (int k4 = 0; k4 < 8; ++k4) {
            float wv[4][4];
            #pragma unroll
            for (int u = 0; u < 4; ++u) {
                float4 wq = *(const float4*)&wl[g][((s << 5) + (k4 << 2) + u) * 20 + (oP << 2)];
                wv[u][0] = wq.x; wv[u][1] = wq.y; wv[u][2] = wq.z; wv[u][3] = wq.w;
            }
            const int cc = ((k4 ^ sw) << 2);
            float xr[4][4];
            #pragma unroll
            for (int i2 = 0; i2 < 4; ++i2) {
                float4 xq = *(const float4*)&xl[g][(((bP << 2) + i2) << 5) + cc];
                xr[i2][0] = xq.x; xr[i2][1] = xq.y; xr[i2][2] = xq.z; xr[i2][3] = xq.w;
            }
            #pragma unroll
            for (int i2 = 0; i2 < 4; ++i2)
                #pragma unroll
                for (int u = 0; u < 4; ++u)
                    #pragma unroll
                    for (int j = 0; j < 4; ++j)
                        acc[i2][j] += xr[i2][u] * wv[u][j];
        }
    }

    if (active) {
        #pragma unroll
        for (int i2 = 0; i2 < 4; ++i2) {
            int b = (bP << 2) + i2;
            float4 outv;
            float ov[4];
            #pragma unroll
            for (int j = 0; j < 4; ++j) {
                float v = acc[i2][j] + b0[((oP << 2) + j) * 3025 + loc];
                ov[j] = v > 0.f ? v : 0.f;
            }
            outv.x = ov[0]; outv.y = ov[1]; outv.z = ov[2]; outv.w = ov[3];
            // flatten: row = 4*oh + oP ; col = 4*ow + (o&3)
            *(float4*)(y0 + b * 48400 + ((oh << 2) + oP) * 220 + (ow << 2)) = outv;
        }
    }
}

// ======================= per-sample mean / rstd =============================
__global__ void k_stats(const float* __restrict__ src, float2* __restrict__ stats, int count)
{
    const int b = blockIdx.x, t = threadIdx.x;
    const float* p = src + (long)b * count;
    const int nq = count >> 2;
    float s = 0.f, s2 = 0.f;
    for (int i = t; i < nq; i += 256) {
        float4 v = *(const float4*)(p + (i << 2));
        s  += (v.x + v.y) + (v.z + v.w);
        s2 += (v.x * v.x + v.y * v.y) + (v.z * v.z + v.w * v.w);
    }
    if (t == 0 && (count & 3)) {
        for (int i = nq << 2; i < count; ++i) { float v = p[i]; s += v; s2 += v * v; }
    }
    #pragma unroll
    for (int off = 32; off > 0; off >>= 1) {
        s  += __shfl_down(s,  off, 64);
        s2 += __shfl_down(s2, off, 64);
    }
    __shared__ float rs[4], rs2[4];
    if ((t & 63) == 0) { rs[t >> 6] = s; rs2[t >> 6] = s2; }
    __syncthreads();
    if (t == 0) {
        float S  = rs[0] + rs[1] + rs[2] + rs[3];
        float S2 = rs2[0] + rs2[1] + rs2[2] + rs2[3];
        float m  = S / count;
        float var = S2 / count - m * m;
        stats[b] = make_float2(m, rsqrtf(var + 1e-5f));
    }
}

// =============== layer0: normalize + affine + 2x2 maxpool ===================
__global__ void k_pool(const float* __restrict__ y0, const float2* __restrict__ st,
                       const float* __restrict__ g0, const float* __restrict__ be0,
                       float* __restrict__ P)
{
    int idx = blockIdx.x * 256 + threadIdx.x;
    if (idx >= 128 * 110 * 110) return;
    int b = idx / 12100, r = idx % 12100;
    int ph = r / 110, pw = r % 110;
    float2 s = st[b];
    int gb = (ph * 220 + pw) * 2;        // 2ph*220 + 2pw
    const float* yb = y0 + b * 48400 + gb;
    float2 a0 = *(const float2*)yb;
    float2 a1 = *(const float2*)(yb + 220);
    float2 ga0 = *(const float2*)(g0 + gb),  ga1 = *(const float2*)(g0 + gb + 220);
    float2 ba0 = *(const float2*)(be0 + gb), ba1 = *(const float2*)(be0 + gb + 220);
    float n0 = (a0.x - s.x) * s.y * ga0.x + ba0.x;
    float n1 = (a0.y - s.x) * s.y * ga0.y + ba0.y;
    float n2 = (a1.x - s.x) * s.y * ga1.x + ba1.x;
    float n3 = (a1.y - s.x) * s.y * ga1.y + ba1.y;
    P[idx] = fmaxf(fmaxf(n0, n1), fmaxf(n2, n3));
}

// ======================= conv1: locally connected layer 1 ===================
// block = 128 thr (lane = b), one (oh,ow) location; 9 o, K=36.
__global__ __launch_bounds__(128) void k_conv1(const float* __restrict__ P,
                                               const float* __restrict__ w1,
                                               const float* __restrict__ b1,
                                               float* __restrict__ y1)
{
    __shared__ float wloc[324];
    __shared__ float pat[128 * 64];      // [b][16 chunks] XOR-swizzled
    const int t = threadIdx.x;
    const int loc = blockIdx.x;
    const int oh = loc / 53, ow = loc % 53;
    for (int e = t; e < 324; e += 128) wloc[e] = w1[loc * 324 + e];
    #pragma unroll
    for (int i = 0; i < 9; ++i) {
        int q = t + (i << 7);            // [0,1152)
        int b_r = q / 9, c = q % 9;
        float pv[4];
        #pragma unroll
        for (int u = 0; u < 4; ++u) {
            int sidx = (c << 2) + u;     // < 36
            int ki = sidx / 6, kj = sidx % 6;
            pv[u] = P[b_r * 12100 + ((oh << 1) + ki) * 110 + (ow << 1) + kj];
        }
        float4 pq; pq.x = pv[0]; pq.y = pv[1]; pq.z = pv[2]; pq.w = pv[3];
        *(float4*)&pat[(b_r << 6) + ((c ^ (b_r & 15)) << 2)] = pq;
    }
    __syncthreads();
    const int b = t;
    float acc[9];
    #pragma unroll
    for (int o = 0; o < 9; ++o) acc[o] = b1[o * 2809 + loc];
    #pragma unroll
    for (int s4 = 0; s4 < 9; ++s4) {
        float4 pq = *(const float4*)&pat[(b << 6) + ((s4 ^ (b & 15)) << 2)];
        #pragma unroll
        for (int o = 0; o < 9; ++o) {
            float4 wq = *(const float4*)&wloc[o * 36 + (s4 << 2)];
            acc[o] += pq.x * wq.x + pq.y * wq.y + pq.z * wq.z + pq.w * wq.w;
        }
    }
    #pragma unroll
    for (int o = 0; o < 9; ++o) {
        float v = acc[o] > 0.f ? acc[o] : 0.f;
        // flatten 3x3: row = 3*oh + o/3, col = 3*ow + o%3
        y1[b * 25281 + (3 * oh + o / 3) * 159 + 3 * ow + o % 3] = v;
    }
}

// ============ layer1 normalize -> hb[b][25600] (bf16, zero-padded) ==========
__global__ void k_normb(const float* __restrict__ y1, const float2* __restrict__ st,
                        const float* __restrict__ g1, const float* __restrict__ be1,
                        unsigned short* __restrict__ hb)
{
    int idx = blockIdx.x * 256 + threadIdx.x;   // < 128*25600
    int b = idx / 25600, k = idx % 25600;
    float v = 0.f;
    if (k < 25281) {
        float2 s = st[b];
        v = (y1[b * 25281 + k] - s.x) * s.y * g1[k] + be1[k];
    }
    hb[idx] = (unsigned short)f2bf(v);
}

// =============== FC: 128x1000 GEMM, bf16 MFMA, K-split 50 ===================
// grid = (16 n-blocks of 64) x (50 k-splits of 512); 256 thr = 4 waves.
// wave owns a 16-col stripe x full M=128 (8 MFMA 16x16x32 tiles, no LDS).
// fcw converted fp32->bf16 on the fly (fetched once); hb is bf16, L2/L3-hot.
__global__ __launch_bounds__(256) void k_fc_mfma(const unsigned short* __restrict__ hb,
                                                 const float* __restrict__ fcw,
                                                 float* __restrict__ pp)
{
    const int lane = threadIdx.x & 63;
    const int wave = threadIdx.x >> 6;
    const int n0   = (blockIdx.x << 6) + (wave << 4);   // wave's col base
    const int k0   = blockIdx.y << 9;                   // 512 K per block
    const int m16  = lane & 15;
    const int q    = lane >> 4;                         // 0..3
    const int nc   = n0 + m16;                          // this lane's col
    const int nrow = nc < 1000 ? nc : 999;              // clamp (cols>=1000 ignored)
    const long wrow = (long)nrow * 25281;

    float4v acc[8];
    #pragma unroll
    for (int i = 0; i < 8; ++i) acc[i] = (float4v){0.f, 0.f, 0.f, 0.f};

    const unsigned short* ha = hb + m16 * 25600;        // A row for this lane

    for (int c = 0; c < 16; ++c) {                      // 16 k-chunks of 32
        const int kb = k0 + (c << 5) + (q << 3);        // this lane's 8-k base
        // ---- B fragment: fcw[nrow][kb..kb+7], fp32 -> bf16 (row stride odd
        //      => scalar dword loads; 4 quads/row still cover 128B contiguous)
        long widx = wrow + kb;
        short8 bf;
        if (widx + 8 <= 25281000L) {
            #pragma unroll
            for (int j = 0; j < 8; ++j) bf[j] = f2bf(fcw[widx + j]);
        } else {                                        // tail of last row only
            #pragma unroll
            for (int j = 0; j < 8; ++j) {
                long e = widx + j;
                bf[j] = f2bf(e < 25281000L ? fcw[e] : 0.f);
            }
        }
        // ---- A fragments (bf16 direct, 16B aligned) + 8 MFMAs over M=128
        #pragma unroll
        for (int mt = 0; mt < 8; ++mt) {
            short8 af = *(const short8*)(ha + mt * 16 * 25600 + kb);
            acc[mt] = __builtin_amdgcn_mfma_f32_16x16x32_bf16(af, bf, acc[mt], 0, 0, 0);
        }
    }

    // ---- store partials: D row = q*4+i (within 16-tile), col = m16
    float* prow = pp + ((size_t)blockIdx.y << 17);      // [bz][128][1024]
    #pragma unroll
    for (int mt = 0; mt < 8; ++mt) {
        const int mb = (mt << 4) + (q << 2);
        #pragma unroll
        for (int i = 0; i < 4; ++i)
            prow[(size_t)(mb + i) * 1024 + nc] = acc[mt][i];
    }
}

// ================= reduce K-partials + bias + softmax =======================
__global__ void k_softmax(const float* __restrict__ partials, const float* __restrict__ fcb,
                          float* __restrict__ out)
{
    const int b = blockIdx.x, t = threadIdx.x;
    float v[4];
    float mx = -3.4e38f;
    #pragma unroll
    for (int i = 0; i < 4; ++i) {
        int o = t + (i << 8);
        float s = -3.4e38f;
        if (o < 1000) {
            s = fcb[o];
            for (int bz = 0; bz < 50; ++bz)
                s += partials[(((bz << 7) + b) << 10) + o];
        }
        v[i] = s;
        mx = fmaxf(mx, s);
    }
    __shared__ float red[4], red2[4];
    #pragma unroll
    for (int off = 32; off > 0; off >>= 1) mx = fmaxf(mx, __shfl_down(mx, off, 64));
    if ((t & 63) == 0) red[t >> 6] = mx;
    __syncthreads();
    float M = fmaxf(fmaxf(red[0], red[1]), fmaxf(red[2], red[3]));
    float se = 0.f;
    #pragma unroll
    for (int i = 0; i < 4; ++i) {
        int o = t + (i << 8);
        if (o < 1000) { v[i] = expf(v[i] - M); se += v[i]; }
    }
    #pragma unroll
    for (int off = 32; off > 0; off >>= 1) se += __shfl_down(se, off, 64);
    if ((t & 63) == 0) red2[t >> 6] = se;
    __syncthreads();
    float inv = 1.f / (red2[0] + red2[1] + red2[2] + red2[3]);
    #pragma unroll
    for (int i = 0; i < 4; ++i) {
        int o = t + (i << 8);
        if (o < 1000) out[b * 1000 + o] = v[i] * inv;
    }
}

// ===========================================================================
extern "C" void kernel_launch(void* const* d_in, const int* in_sizes, int n_in,
                              void* d_out, int out_size, void* d_ws, size_t ws_size,
                              hipStream_t stream)
{
    const float* x   = (const float*)d_in[0];
    const float* w0  = (const float*)d_in[1];
    const float* b0  = (const float*)d_in[2];
    const float* g0  = (const float*)d_in[3];
    const float* be0 = (const float*)d_in[4];
    const float* w1  = (const float*)d_in[5];
    const float* b1  = (const float*)d_in[6];
    const float* g1  = (const float*)d_in[7];
    const float* be1 = (const float*)d_in[8];
    const float* fcw = (const float*)d_in[9];
    const float* fcb = (const float*)d_in[10];
    float* out = (float*)d_out;
    float* ws  = (float*)d_ws;

    // workspace layout (floats), max 12,618,880 (~50.5 MB):
    //   y0  [0 .. 6,195,200)                 128*220*220
    //   st0 [6,195,200 .. 6,195,456)         128 float2
    //   P   [6,195,456 .. 7,744,256)         128*110*110
    //   y1  [7,744,256 .. 10,980,224)        128*159*159
    //   st1 [10,980,224 .. 10,980,480)       128 float2
    //   hb  [10,980,480 .. 12,618,880)       128*25600 bf16 (ushort)
    //   pp  [0 .. 6,553,600)                 50*128*1024 -- overlays y0/st0/P
    //       (y0/st0/P are dead before k_fc_mfma runs)
    float*  y0  = ws;
    float2* st0 = (float2*)(ws + 6195200);
    float*  P   = ws + 6195456;
    float*  y1  = ws + 7744256;
    float2* st1 = (float2*)(ws + 10980224);
    unsigned short* hb = (unsigned short*)(ws + 10980480);
    float*  pp  = ws;

    hipLaunchKernelGGL(k_conv0,   dim3(1513),    dim3(256), 0, stream, x, w0, b0, y0);
    hipLaunchKernelGGL(k_stats,   dim3(128),     dim3(256), 0, stream, y0, st0, 48400);
    hipLaunchKernelGGL(k_pool,    dim3(6050),    dim3(256), 0, stream, y0, st0, g0, be0, P);
    hipLaunchKernelGGL(k_conv1,   dim3(2809),    dim3(128), 0, stream, P, w1, b1, y1);
    hipLaunchKernelGGL(k_stats,   dim3(128),     dim3(256), 0, stream, y1, st1, 25281);
    hipLaunchKernelGGL(k_normb,   dim3(12800),   dim3(256), 0, stream, y1, st1, g1, be1, hb);
    hipLaunchKernelGGL(k_fc_mfma, dim3(16, 50),  dim3(256), 0, stream, hb, fcw, pp);
    hipLaunchKernelGGL(k_softmax, dim3(128),     dim3(256), 0, stream, pp, fcb, out);
}

// Round 5
// 500.671 us; speedup vs baseline: 1.2555x; 1.1427x over previous
//
#include <hip/hip_runtime.h>

// ---------------------------------------------------------------------------
// AllTnn: locally-connected net, B=128, fp32 (FC via bf16 MFMA).
//  L0: x[128,3,224,224] * w0[55,55,16,3,8,8] (s4) + b0 -> [128,16,55,55]
//      flatten 4x4 -> [128,220,220], relu, LN(220x220)*g0+be0, maxpool2 -> P[128,110,110]
//  L1: P * w1[53,53,9,1,6,6] (s2) + b1 -> [128,9,53,53]
//      flatten 3x3 -> [128,159,159], relu, LN(159x159)*g1+be1
//  FC: [128,25281] @ fcw[1000,25281]^T + fcb -> softmax -> out[128,1000]
// ---------------------------------------------------------------------------

typedef __attribute__((ext_vector_type(8))) short short8;
typedef __attribute__((ext_vector_type(4))) float float4v;

__device__ __forceinline__ short f2bf(float f) {
    unsigned u = __float_as_uint(f);
    u += 0x7FFFu + ((u >> 16) & 1u);        // round-to-nearest-even
    return (short)(u >> 16);
}

// ======================= conv0: locally connected layer 0 ===================
// block = 256 thr = 2 sub-blocks of 128, each one (oh,ow) location (pairing
// keeps overlapping x lines + shared y0 store lines on one CU: R2 measured
// 322+37 MB vs 699+337 MB unpaired).
// NO x staging: thread (bP,oP) loads its own 4 b-rows x 4 k float4s straight
// from global in the k4 loop. 4 oP-lanes share one address (broadcast), the
// pair-partner shares lines via L1 (~20 KB footprint). w stays in LDS
// (staged once, single barrier) -> NO barriers in the K loop; 30.7 KB LDS
// -> 5 blocks/CU = 20 waves/CU; latency self-hides, R4's prefetch-vs-barrier
// traffic pathology is structurally gone.
__global__ __launch_bounds__(256) void k_conv0(const float* __restrict__ x,
                                               const float* __restrict__ w0,
                                               const float* __restrict__ b0,
                                               float* __restrict__ y0)
{
    __shared__ float wl[2][192 * 20];
    const int g = threadIdx.x >> 7;
    const int t = threadIdx.x & 127;
    int loc = blockIdx.x * 2 + g;
    const bool active = (loc < 3025);
    if (!active) loc = 3024;              // clamp: valid addresses, writes guarded
    const int oh = loc / 55, ow = loc % 55;
    const float* wbase = w0 + loc * 3072;

    // stage w: [k][o] stride 20. 768 float4 quads, 6 per thread.
    #pragma unroll
    for (int i = 0; i < 6; ++i) {
        int q   = t + (i << 7);
        int o_r = q & 15;
        int kq  = q >> 4;                 // [0,48)
        float4 wv = *(const float4*)(wbase + o_r * 192 + (kq << 2));
        wl[g][(kq * 4 + 0) * 20 + o_r] = wv.x;
        wl[g][(kq * 4 + 1) * 20 + o_r] = wv.y;
        wl[g][(kq * 4 + 2) * 20 + o_r] = wv.z;
        wl[g][(kq * 4 + 3) * 20 + o_r] = wv.w;
    }
    __syncthreads();                      // w ready; no more barriers

    const int oP = t & 3;        // o quad base = oP*4
    const int bP = t >> 2;       // b quad base = bP*4, [0,32)
    float acc[4][4] = {};

    // x row base for this location: x + (b*3+ch)*224*224 + (4oh+rw)*224 + 4ow
    const float* xloc = x + (oh << 2) * 224 + (ow << 2);

    #pragma unroll 2
    for (int c = 0; c < 48; ++c) {        // k quad index: k = 4c
        const int ch  = c >> 4;           // channel
        const int rw  = (c >> 1) & 7;     // kernel row
        const int col = (c & 1) << 2;     // 0 or 4
        const float* xp = xloc + (ch * 224 + rw) * 224 + col;
        // 4 direct global loads (L1-hot: shared across oP lanes + pair loc)
        float4 xq[4];
        #pragma unroll
        for (int i2 = 0; i2 < 4; ++i2)
            xq[i2] = *(const float4*)(xp + (((bP << 2) + i2) * 3) * 50176);
        // w quads for this k4
        float wv[4][4];
        #pragma unroll
        for (int u = 0; u < 4; ++u) {
            float4 wq = *(const float4*)&wl[g][((c << 2) + u) * 20 + (oP << 2)];
            wv[u][0] = wq.x; wv[u][1] = wq.y; wv[u][2] = wq.z; wv[u][3] = wq.w;
        }
        #pragma unroll
        for (int i2 = 0; i2 < 4; ++i2) {
            const float xr[4] = {xq[i2].x, xq[i2].y, xq[i2].z, xq[i2].w};
            #pragma unroll
            for (int u = 0; u < 4; ++u)
                #pragma unroll
                for (int j = 0; j < 4; ++j)
                    acc[i2][j] += xr[u] * wv[u][j];
        }
    }

    if (active) {
        #pragma unroll
        for (int i2 = 0; i2 < 4; ++i2) {
            int b = (bP << 2) + i2;
            float4 outv;
            float ov[4];
            #pragma unroll
            for (int j = 0; j < 4; ++j) {
                float v = acc[i2][j] + b0[((oP << 2) + j) * 3025 + loc];
                ov[j] = v > 0.f ? v : 0.f;
            }
            outv.x = ov[0]; outv.y = ov[1]; outv.z = ov[2]; outv.w = ov[3];
            // flatten: row = 4*oh + oP ; col = 4*ow + (o&3)
            *(float4*)(y0 + b * 48400 + ((oh << 2) + oP) * 220 + (ow << 2)) = outv;
        }
    }
}

// ======================= per-sample mean / rstd =============================
__global__ void k_stats(const float* __restrict__ src, float2* __restrict__ stats, int count)
{
    const int b = blockIdx.x, t = threadIdx.x;
    const float* p = src + (long)b * count;
    const int nq = count >> 2;
    float s = 0.f, s2 = 0.f;
    for (int i = t; i < nq; i += 256) {
        float4 v = *(const float4*)(p + (i << 2));
        s  += (v.x + v.y) + (v.z + v.w);
        s2 += (v.x * v.x + v.y * v.y) + (v.z * v.z + v.w * v.w);
    }
    if (t == 0 && (count & 3)) {
        for (int i = nq << 2; i < count; ++i) { float v = p[i]; s += v; s2 += v * v; }
    }
    #pragma unroll
    for (int off = 32; off > 0; off >>= 1) {
        s  += __shfl_down(s,  off, 64);
        s2 += __shfl_down(s2, off, 64);
    }
    __shared__ float rs[4], rs2[4];
    if ((t & 63) == 0) { rs[t >> 6] = s; rs2[t >> 6] = s2; }
    __syncthreads();
    if (t == 0) {
        float S  = rs[0] + rs[1] + rs[2] + rs[3];
        float S2 = rs2[0] + rs2[1] + rs2[2] + rs2[3];
        float m  = S / count;
        float var = S2 / count - m * m;
        stats[b] = make_float2(m, rsqrtf(var + 1e-5f));
    }
}

// =============== layer0: normalize + affine + 2x2 maxpool ===================
__global__ void k_pool(const float* __restrict__ y0, const float2* __restrict__ st,
                       const float* __restrict__ g0, const float* __restrict__ be0,
                       float* __restrict__ P)
{
    int idx = blockIdx.x * 256 + threadIdx.x;
    if (idx >= 128 * 110 * 110) return;
    int b = idx / 12100, r = idx % 12100;
    int ph = r / 110, pw = r % 110;
    float2 s = st[b];
    int gb = (ph * 220 + pw) * 2;        // 2ph*220 + 2pw
    const float* yb = y0 + b * 48400 + gb;
    float2 a0 = *(const float2*)yb;
    float2 a1 = *(const float2*)(yb + 220);
    float2 ga0 = *(const float2*)(g0 + gb),  ga1 = *(const float2*)(g0 + gb + 220);
    float2 ba0 = *(const float2*)(be0 + gb), ba1 = *(const float2*)(be0 + gb + 220);
    float n0 = (a0.x - s.x) * s.y * ga0.x + ba0.x;
    float n1 = (a0.y - s.x) * s.y * ga0.y + ba0.y;
    float n2 = (a1.x - s.x) * s.y * ga1.x + ba1.x;
    float n3 = (a1.y - s.x) * s.y * ga1.y + ba1.y;
    P[idx] = fmaxf(fmaxf(n0, n1), fmaxf(n2, n3));
}

// ======================= conv1: locally connected layer 1 ===================
// block = 128 thr (lane = b), one (oh,ow) location; 9 o, K=36.
__global__ __launch_bounds__(128) void k_conv1(const float* __restrict__ P,
                                               const float* __restrict__ w1,
                                               const float* __restrict__ b1,
                                               float* __restrict__ y1)
{
    __shared__ float wloc[324];
    __shared__ float pat[128 * 64];      // [b][16 chunks] XOR-swizzled
    const int t = threadIdx.x;
    const int loc = blockIdx.x;
    const int oh = loc / 53, ow = loc % 53;
    for (int e = t; e < 324; e += 128) wloc[e] = w1[loc * 324 + e];
    #pragma unroll
    for (int i = 0; i < 9; ++i) {
        int q = t + (i << 7);            // [0,1152)
        int b_r = q / 9, c = q % 9;
        float pv[4];
        #pragma unroll
        for (int u = 0; u < 4; ++u) {
            int sidx = (c << 2) + u;     // < 36
            int ki = sidx / 6, kj = sidx % 6;
            pv[u] = P[b_r * 12100 + ((oh << 1) + ki) * 110 + (ow << 1) + kj];
        }
        float4 pq; pq.x = pv[0]; pq.y = pv[1]; pq.z = pv[2]; pq.w = pv[3];
        *(float4*)&pat[(b_r << 6) + ((c ^ (b_r & 15)) << 2)] = pq;
    }
    __syncthreads();
    const int b = t;
    float acc[9];
    #pragma unroll
    for (int o = 0; o < 9; ++o) acc[o] = b1[o * 2809 + loc];
    #pragma unroll
    for (int s4 = 0; s4 < 9; ++s4) {
        float4 pq = *(const float4*)&pat[(b << 6) + ((s4 ^ (b & 15)) << 2)];
        #pragma unroll
        for (int o = 0; o < 9; ++o) {
            float4 wq = *(const float4*)&wloc[o * 36 + (s4 << 2)];
            acc[o] += pq.x * wq.x + pq.y * wq.y + pq.z * wq.z + pq.w * wq.w;
        }
    }
    #pragma unroll
    for (int o = 0; o < 9; ++o) {
        float v = acc[o] > 0.f ? acc[o] : 0.f;
        // flatten 3x3: row = 3*oh + o/3, col = 3*ow + o%3
        y1[b * 25281 + (3 * oh + o / 3) * 159 + 3 * ow + o % 3] = v;
    }
}

// ============ layer1 normalize -> hb[b][25600] (bf16, zero-padded) ==========
__global__ void k_normb(const float* __restrict__ y1, const float2* __restrict__ st,
                        const float* __restrict__ g1, const float* __restrict__ be1,
                        unsigned short* __restrict__ hb)
{
    int idx = blockIdx.x * 256 + threadIdx.x;   // < 128*25600
    int b = idx / 25600, k = idx % 25600;
    float v = 0.f;
    if (k < 25281) {
        float2 s = st[b];
        v = (y1[b * 25281 + k] - s.x) * s.y * g1[k] + be1[k];
    }
    hb[idx] = (unsigned short)f2bf(v);
}

// =============== FC: 128x1000 GEMM, bf16 MFMA, K-split 50 ===================
// grid = (16 n-blocks of 64) x (50 k-splits of 512); 256 thr = 4 waves.
// wave owns a 16-col stripe x full M=128 (8 MFMA 16x16x32 tiles, no LDS).
// fcw converted fp32->bf16 on the fly (fetched once); hb is bf16, L2/L3-hot.
__global__ __launch_bounds__(256) void k_fc_mfma(const unsigned short* __restrict__ hb,
                                                 const float* __restrict__ fcw,
                                                 float* __restrict__ pp)
{
    const int lane = threadIdx.x & 63;
    const int wave = threadIdx.x >> 6;
    const int n0   = (blockIdx.x << 6) + (wave << 4);   // wave's col base
    const int k0   = blockIdx.y << 9;                   // 512 K per block
    const int m16  = lane & 15;
    const int q    = lane >> 4;                         // 0..3
    const int nc   = n0 + m16;                          // this lane's col
    const int nrow = nc < 1000 ? nc : 999;              // clamp (cols>=1000 ignored)
    const long wrow = (long)nrow * 25281;

    float4v acc[8];
    #pragma unroll
    for (int i = 0; i < 8; ++i) acc[i] = (float4v){0.f, 0.f, 0.f, 0.f};

    const unsigned short* ha = hb + m16 * 25600;        // A row for this lane

    for (int c = 0; c < 16; ++c) {                      // 16 k-chunks of 32
        const int kb = k0 + (c << 5) + (q << 3);        // this lane's 8-k base
        // ---- B fragment: fcw[nrow][kb..kb+7], fp32 -> bf16 (row stride odd
        //      => scalar dword loads; 4 quads/row still cover 128B contiguous)
        long widx = wrow + kb;
        short8 bf;
        if (widx + 8 <= 25281000L) {
            #pragma unroll
            for (int j = 0; j < 8; ++j) bf[j] = f2bf(fcw[widx + j]);
        } else {                                        // tail of last row only
            #pragma unroll
            for (int j = 0; j < 8; ++j) {
                long e = widx + j;
                bf[j] = f2bf(e < 25281000L ? fcw[e] : 0.f);
            }
        }
        // ---- A fragments (bf16 direct, 16B aligned) + 8 MFMAs over M=128
        #pragma unroll
        for (int mt = 0; mt < 8; ++mt) {
            short8 af = *(const short8*)(ha + mt * 16 * 25600 + kb);
            acc[mt] = __builtin_amdgcn_mfma_f32_16x16x32_bf16(af, bf, acc[mt], 0, 0, 0);
        }
    }

    // ---- store partials: D row = q*4+i (within 16-tile), col = m16
    float* prow = pp + ((size_t)blockIdx.y << 17);      // [bz][128][1024]
    #pragma unroll
    for (int mt = 0; mt < 8; ++mt) {
        const int mb = (mt << 4) + (q << 2);
        #pragma unroll
        for (int i = 0; i < 4; ++i)
            prow[(size_t)(mb + i) * 1024 + nc] = acc[mt][i];
    }
}

// ================= reduce K-partials + bias + softmax =======================
__global__ void k_softmax(const float* __restrict__ partials, const float* __restrict__ fcb,
                          float* __restrict__ out)
{
    const int b = blockIdx.x, t = threadIdx.x;
    float v[4];
    float mx = -3.4e38f;
    #pragma unroll
    for (int i = 0; i < 4; ++i) {
        int o = t + (i << 8);
        float s = -3.4e38f;
        if (o < 1000) {
            s = fcb[o];
            for (int bz = 0; bz < 50; ++bz)
                s += partials[(((bz << 7) + b) << 10) + o];
        }
        v[i] = s;
        mx = fmaxf(mx, s);
    }
    __shared__ float red[4], red2[4];
    #pragma unroll
    for (int off = 32; off > 0; off >>= 1) mx = fmaxf(mx, __shfl_down(mx, off, 64));
    if ((t & 63) == 0) red[t >> 6] = mx;
    __syncthreads();
    float M = fmaxf(fmaxf(red[0], red[1]), fmaxf(red[2], red[3]));
    float se = 0.f;
    #pragma unroll
    for (int i = 0; i < 4; ++i) {
        int o = t + (i << 8);
        if (o < 1000) { v[i] = expf(v[i] - M); se += v[i]; }
    }
    #pragma unroll
    for (int off = 32; off > 0; off >>= 1) se += __shfl_down(se, off, 64);
    if ((t & 63) == 0) red2[t >> 6] = se;
    __syncthreads();
    float inv = 1.f / (red2[0] + red2[1] + red2[2] + red2[3]);
    #pragma unroll
    for (int i = 0; i < 4; ++i) {
        int o = t + (i << 8);
        if (o < 1000) out[b * 1000 + o] = v[i] * inv;
    }
}

// ===========================================================================
extern "C" void kernel_launch(void* const* d_in, const int* in_sizes, int n_in,
                              void* d_out, int out_size, void* d_ws, size_t ws_size,
                              hipStream_t stream)
{
    const float* x   = (const float*)d_in[0];
    const float* w0  = (const float*)d_in[1];
    const float* b0  = (const float*)d_in[2];
    const float* g0  = (const float*)d_in[3];
    const float* be0 = (const float*)d_in[4];
    const float* w1  = (const float*)d_in[5];
    const float* b1  = (const float*)d_in[6];
    const float* g1  = (const float*)d_in[7];
    const float* be1 = (const float*)d_in[8];
    const float* fcw = (const float*)d_in[9];
    const float* fcb = (const float*)d_in[10];
    float* out = (float*)d_out;
    float* ws  = (float*)d_ws;

    // workspace layout (floats), max 12,618,880 (~50.5 MB):
    //   y0  [0 .. 6,195,200)                 128*220*220
    //   st0 [6,195,200 .. 6,195,456)         128 float2
    //   P   [6,195,456 .. 7,744,256)         128*110*110
    //   y1  [7,744,256 .. 10,980,224)        128*159*159
    //   st1 [10,980,224 .. 10,980,480)       128 float2
    //   hb  [10,980,480 .. 12,618,880)       128*25600 bf16 (ushort)
    //   pp  [0 .. 6,553,600)                 50*128*1024 -- overlays y0/st0/P
    //       (y0/st0/P are dead before k_fc_mfma runs)
    float*  y0  = ws;
    float2* st0 = (float2*)(ws + 6195200);
    float*  P   = ws + 6195456;
    float*  y1  = ws + 7744256;
    float2* st1 = (float2*)(ws + 10980224);
    unsigned short* hb = (unsigned short*)(ws + 10980480);
    float*  pp  = ws;

    hipLaunchKernelGGL(k_conv0,   dim3(1513),    dim3(256), 0, stream, x, w0, b0, y0);
    hipLaunchKernelGGL(k_stats,   dim3(128),     dim3(256), 0, stream, y0, st0, 48400);
    hipLaunchKernelGGL(k_pool,    dim3(6050),    dim3(256), 0, stream, y0, st0, g0, be0, P);
    hipLaunchKernelGGL(k_conv1,   dim3(2809),    dim3(128), 0, stream, P, w1, b1, y1);
    hipLaunchKernelGGL(k_stats,   dim3(128),     dim3(256), 0, stream, y1, st1, 25281);
    hipLaunchKernelGGL(k_normb,   dim3(12800),   dim3(256), 0, stream, y1, st1, g1, be1, hb);
    hipLaunchKernelGGL(k_fc_mfma, dim3(16, 50),  dim3(256), 0, stream, hb, fcw, pp);
    hipLaunchKernelGGL(k_softmax, dim3(128),     dim3(256), 0, stream, pp, fcb, out);
}